// Round 3
// baseline (402.667 us; speedup 1.0000x reference)
//
#include <hip/hip_runtime.h>
#include <stdint.h>

// ---- problem constants ----
#define B_N   2
#define HQ_N  32
#define HKV_N 8
#define QL_N  1024
#define SL_N  4096
#define DH_N  128
#define ROPE_N 64
#define RANK_N 512

typedef _Float16 f16;
typedef _Float16 half8 __attribute__((ext_vector_type(8)));
typedef float floatx16 __attribute__((ext_vector_type(16)));
typedef int int2v __attribute__((ext_vector_type(2)));

union H8 { half8 h; uint64_t q[2]; };
union H4 { f16 h[4]; uint64_t q; };
union PKU { f16 h[2]; uint32_t u; };
union BFU { uint32_t u[4]; half8 h; };

// ---------------------------------------------------------------------------
// prep 1: fp32 -> fp16 convert of C_kv_t2 and K_rope_t2
// ---------------------------------------------------------------------------
__global__ __launch_bounds__(256) void k_convert(const float* __restrict__ C,
                                                 const float* __restrict__ Kr,
                                                 f16* __restrict__ Cf,
                                                 f16* __restrict__ Krf) {
  const size_t NC = (size_t)B_N * SL_N * RANK_N;            // 4194304
  size_t idx = ((size_t)blockIdx.x * 256 + threadIdx.x) * 8; // covers 8388608
  const float* src;
  f16* dst;
  if (idx < NC) { src = C + idx;        dst = Cf + idx; }
  else          { src = Kr + (idx - NC); dst = Krf + (idx - NC); }
  float4 a = *(const float4*)(src);
  float4 b = *(const float4*)(src + 4);
  H8 o;
  o.h[0] = (f16)a.x; o.h[1] = (f16)a.y; o.h[2] = (f16)a.z; o.h[3] = (f16)a.w;
  o.h[4] = (f16)b.x; o.h[5] = (f16)b.y; o.h[6] = (f16)b.z; o.h[7] = (f16)b.w;
  *(half8*)dst = o.h;
}

// ---------------------------------------------------------------------------
// prep 2: weights: M2T2 (rotation), WUKh = f16(WUK), WUVT = f16(WUV^T).
// grid = 448 (16384 + 32768 + 65536 elements).
// ---------------------------------------------------------------------------
__global__ __launch_bounds__(256) void k_weights(const float* __restrict__ Ul,
                                                 const float* __restrict__ WUK,
                                                 const float* __restrict__ WUV,
                                                 f16* __restrict__ M2T2,
                                                 f16* __restrict__ WUKh,
                                                 f16* __restrict__ WUVT) {
  int idx = blockIdx.x * 256 + threadIdx.x;
  if (idx < 16384) {
    int c = idx >> 7, d = idx & 127;
    float v = 0.f;
    if (c < 64) { if (d >= 64) v = Ul[c * 64 + (d - 64)]; }
    else        { if (d < 64)  v = Ul[(c - 64) * 64 + d]; }
    M2T2[idx] = (f16)v;
  } else if (idx < 49152) {
    int i = idx - 16384;             // 64*512 flat copy-convert
    WUKh[i] = (f16)WUK[i];
  } else {
    int i = idx - 49152;             // WUVT[c][r] = WUV[r][c]
    int c = i >> 9, r = i & 511;
    WUVT[i] = (f16)WUV[r * 128 + c];
  }
}

// ---------------------------------------------------------------------------
// prep 3: Qeff2 = (f16(Q) @ M2n) * log2(e)  via MFMA.  M=65536, K=128, N=128.
// log2e folded here so the flash softmax uses exp2 directly (applied to the
// f32 accumulator BEFORE the f16 round -> same rounding error as unscaled).
// LDS-transpose epilogue -> b128 global stores.
// ---------------------------------------------------------------------------
__global__ __launch_bounds__(256) void k_qeff(const float* __restrict__ Q,
                                              const f16* __restrict__ M2T2,
                                              f16* __restrict__ Qeff2) {
  __shared__ __align__(16) f16 qs[128 * 132];  // 33792 B
  int t = threadIdx.x;
  int wave = t >> 6, lane = t & 63, l31 = lane & 31, lhi = lane >> 5;
  size_t m0 = (size_t)blockIdx.x * 128;
#pragma unroll
  for (int i = 0; i < 16; i++) {
    int flat = i * 256 + t; int row = flat >> 5, seg = flat & 31;
    float4 v = *(const float4*)(Q + (m0 + row) * DH_N + seg * 4);
    H4 o; o.h[0] = (f16)v.x; o.h[1] = (f16)v.y; o.h[2] = (f16)v.z; o.h[3] = (f16)v.w;
    *(uint64_t*)(qs + row * 132 + seg * 4) = o.q;
  }
  __syncthreads();
  floatx16 acc[4];
#pragma unroll
  for (int ct = 0; ct < 4; ct++)
#pragma unroll
    for (int r = 0; r < 16; r++) acc[ct][r] = 0.f;
#pragma unroll
  for (int kk = 0; kk < 8; ++kk) {
    H8 af;
    const uint64_t* pa = (const uint64_t*)(qs + (wave * 32 + l31) * 132 + kk * 16 + lhi * 8);
    af.q[0] = pa[0]; af.q[1] = pa[1];
#pragma unroll
    for (int ct = 0; ct < 4; ct++) {
      H8 bf; bf.h = *(const half8*)(M2T2 + (size_t)(ct * 32 + l31) * 128 + kk * 16 + lhi * 8);
      acc[ct] = __builtin_amdgcn_mfma_f32_32x32x16_f16(af.h, bf.h, acc[ct], 0, 0, 0);
    }
  }
  __syncthreads();   // done reading qs
  const float LOG2E = 1.44269504f;
#pragma unroll
  for (int ct = 0; ct < 4; ct++)
#pragma unroll
    for (int r = 0; r < 16; r++) {
      int row = (r & 3) + 8 * (r >> 2) + 4 * lhi;
      qs[(wave * 32 + row) * 132 + ct * 32 + l31] = (f16)(acc[ct][r] * LOG2E);
    }
  __syncthreads();
#pragma unroll
  for (int i = 0; i < 8; i++) {
    int flat = i * 256 + t; int row = flat >> 4, ch = flat & 15;
    const uint64_t* src = (const uint64_t*)(qs + row * 132 + ch * 8);
    uint64_t v0 = src[0], v1 = src[1];
    uint64_t* gd = (uint64_t*)(Qeff2 + (m0 + row) * 128 + ch * 8);
    gd[0] = v0; gd[1] = v1;
  }
}

// ---------------------------------------------------------------------------
// prep 4: Kn[b][s][64] = C[b,s,:] @ W_UK^T  (f16, f32 MFMA accum).
// grid = 64 = b(2) x 32 s-tiles(128).  All operands b128 loads (WUKh f16).
// ---------------------------------------------------------------------------
__global__ __launch_bounds__(256) void k_kn(const f16* __restrict__ Cf,
                                            const f16* __restrict__ WUKh,
                                            f16* __restrict__ Kn) {
  int t = threadIdx.x;
  int wave = t >> 6, lane = t & 63, l31 = lane & 31, lhi = lane >> 5;
  int b = blockIdx.x >> 5, st = blockIdx.x & 31;
  int s0 = st * 128;
  const f16* Cb = Cf + ((size_t)b * SL_N + s0 + wave * 32) * RANK_N;
  floatx16 acc[2];
#pragma unroll
  for (int ct = 0; ct < 2; ct++)
#pragma unroll
    for (int r = 0; r < 16; r++) acc[ct][r] = 0.f;
#pragma unroll 4
  for (int kk = 0; kk < 32; ++kk) {
    H8 af; af.h = *(const half8*)(Cb + (size_t)l31 * RANK_N + kk * 16 + lhi * 8);
#pragma unroll
    for (int ct = 0; ct < 2; ct++) {
      H8 bf; bf.h = *(const half8*)(WUKh + (size_t)(ct * 32 + l31) * RANK_N + kk * 16 + lhi * 8);
      acc[ct] = __builtin_amdgcn_mfma_f32_32x32x16_f16(af.h, bf.h, acc[ct], 0, 0, 0);
    }
  }
#pragma unroll
  for (int ct = 0; ct < 2; ct++)
#pragma unroll
    for (int r = 0; r < 16; r++) {
      int row = (r & 3) + 8 * (r >> 2) + 4 * lhi;
      Kn[((size_t)b * SL_N + s0 + wave * 32 + row) * 64 + ct * 32 + l31] = (f16)acc[ct][r];
    }
}

// ---------------------------------------------------------------------------
// prep 5: CW^T[b][c][s] = (C[b] @ W_UV)^T in fp16, via MFMA.
// B-frags now contiguous b128 from WUVT (pre-transposed f16).
// ---------------------------------------------------------------------------
__global__ __launch_bounds__(256) void k_cw(const f16* __restrict__ Cf,
                                            const f16* __restrict__ WUVT,
                                            f16* __restrict__ CWT) {
  __shared__ float ot[32 * 132];   // 16896 B
  int t = threadIdx.x;
  int wave = t >> 6, lane = t & 63, l31 = lane & 31, lhi = lane >> 5;
  int b = blockIdx.x >> 7, st = blockIdx.x & 127;
  int s0 = st * 32;
  const f16* Cb = Cf + ((size_t)b * SL_N + s0) * RANK_N;
  floatx16 acc;
#pragma unroll
  for (int r = 0; r < 16; r++) acc[r] = 0.f;
#pragma unroll 4
  for (int kk = 0; kk < 32; ++kk) {
    H8 af; af.h = *(const half8*)(Cb + (size_t)l31 * RANK_N + kk * 16 + lhi * 8);
    H8 bf; bf.h = *(const half8*)(WUVT + (size_t)(wave * 32 + l31) * RANK_N + kk * 16 + lhi * 8);
    acc = __builtin_amdgcn_mfma_f32_32x32x16_f16(af.h, bf.h, acc, 0, 0, 0);
  }
#pragma unroll
  for (int r = 0; r < 16; r++)
    ot[((r & 3) + 8 * (r >> 2) + 4 * lhi) * 132 + wave * 32 + l31] = acc[r];
  __syncthreads();
  int c = t >> 1, sh = t & 1;
  H8 o0, o1;
#pragma unroll
  for (int j = 0; j < 8; j++) o0.h[j] = (f16)ot[(sh * 16 + j) * 132 + c];
#pragma unroll
  for (int j = 0; j < 8; j++) o1.h[j] = (f16)ot[(sh * 16 + 8 + j) * 132 + c];
  f16* dst = CWT + ((size_t)b * DH_N + c) * SL_N + s0 + sh * 16;
  *(half8*)dst = o0.h;
  *(half8*)(dst + 8) = o1.h;
}

// ---------------------------------------------------------------------------
// flash kernel: K path fully register-resident (per-wave global loads,
// L1 dedups the 4-wave duplicate reads) -> no kbuf, no S^T LDS reads,
// SINGLE barrier per iter (protects double-buffered cbuf only).
// Softmax in base-2 (Qeff2 pre-scaled by log2e).  P via pack+permlane32.
// LDS 34 KB (cbuf pair, epilogue alias).  grid = 512 = (b, h, q-tile 128).
// ---------------------------------------------------------------------------
#define CROW 36

__global__ __launch_bounds__(256, 2) void k_flash(
    const f16* __restrict__ Qeff2, const f16* __restrict__ Kn,
    const f16* __restrict__ Krf, const f16* __restrict__ CWT,
    float* __restrict__ out) {
  __shared__ __align__(16) char smem[34048];
  f16* cbuf0 = (f16*)smem;                    // [128][36] 9216 B
  f16* cbuf1 = (f16*)(smem + 9216);
  float* ot  = (float*)smem;                  // epilogue [64][133] 34048 B

  int t = threadIdx.x;
  int wave = t >> 6, lane = t & 63, l31 = lane & 31, lhi = lane >> 5;
  int qt = blockIdx.x & 7; int h = (blockIdx.x >> 3) & 31; int b = blockIdx.x >> 8;
  int kv = h >> 2;
  int qloc = wave * 32 + l31;

  const f16* Knb = Kn + (size_t)b * SL_N * 64;
  const f16* Kb  = Krf + (size_t)(b * HKV_N + kv) * SL_N * ROPE_N;
  const f16* Wb  = CWT + (size_t)b * DH_N * SL_N;

  // persistent Q fragments (B-operand), K = 128, pre-scaled by log2e
  half8 qf[8];
  {
    const f16* qrow = Qeff2 + ((size_t)(b * HQ_N + h) * QL_N + qt * 128 + qloc) * 128 + lhi * 8;
#pragma unroll
    for (int kk = 0; kk < 8; kk++) qf[kk] = *(const half8*)(qrow + kk * 16);
  }

  floatx16 oacc[4];
#pragma unroll
  for (int ct = 0; ct < 4; ct++)
#pragma unroll
    for (int r = 0; r < 16; r++) oacc[ct][r] = 0.f;
  float m_run = -1e30f, l_run = 0.f;

  int cA = t >> 2, cch = t & 3;   // cwt staging: rows cA and 64+cA, cols cch*8
  const f16* pKn = Knb + (size_t)l31 * 64 + lhi * 8;   // A-frag row = s0+l31
  const f16* pKr = Kb  + (size_t)l31 * 64 + lhi * 8;
  const f16* pW0 = Wb + (size_t)cA * SL_N + cch * 8;
  const f16* pW1 = Wb + (size_t)(64 + cA) * SL_N + cch * 8;

  H8 kA[8], kB[8];
  // ---- preload tile 0: K frags to regs, CWT tile to cbuf0 ----
#pragma unroll
  for (int kk = 0; kk < 4; kk++) {
    kA[kk].h     = *(const half8*)(pKn + kk * 16);
    kA[4 + kk].h = *(const half8*)(pKr + kk * 16);
  }
  {
    H8 c0, c1;
    c0.h = *(const half8*)(pW0);
    c1.h = *(const half8*)(pW1);
    uint64_t* e0 = (uint64_t*)(cbuf0 + cA * CROW + cch * 8);
    e0[0] = c0.q[0]; e0[1] = c0.q[1];
    uint64_t* e1 = (uint64_t*)(cbuf0 + (64 + cA) * CROW + cch * 8);
    e1[0] = c1.q[0]; e1[1] = c1.q[1];
  }
  __syncthreads();

  auto step = [&](H8 (&kcur)[8], H8 (&knxt)[8], f16* cc, f16* cn, int it) {
    bool pre = it < 127;
    int s0n = (it + 1) * 32;
    H8 c0, c1;
    if (pre) {   // issue next-tile loads; consumed at commit / next S^T
      size_t koff = (size_t)s0n * 64;
#pragma unroll
      for (int kk = 0; kk < 4; kk++) {
        knxt[kk].h     = *(const half8*)(pKn + koff + kk * 16);
        knxt[4 + kk].h = *(const half8*)(pKr + koff + kk * 16);
      }
      c0.h = *(const half8*)(pW0 + s0n);
      c1.h = *(const half8*)(pW1 + s0n);
    }

    // ---- S^T = K_eff(A) . Q^T(B), K = 128 -- registers only ----
    floatx16 sa;
#pragma unroll
    for (int r = 0; r < 16; r++) sa[r] = 0.f;
#pragma unroll
    for (int kk = 0; kk < 8; kk++)
      sa = __builtin_amdgcn_mfma_f32_32x32x16_f16(kcur[kk].h, qf[kk], sa, 0, 0, 0);

    // ---- online softmax, base-2 (q in lane, s in regs + partner xor32) ----
    float mt = -1e30f;
#pragma unroll
    for (int r = 0; r < 16; r++) mt = fmaxf(mt, sa[r]);
    mt = fmaxf(mt, __shfl_xor(mt, 32, 64));
    if (__any(mt > m_run)) {   // strict defer-rescale (exact)
      float m_new = fmaxf(m_run, mt);
      float alpha = exp2f(m_run - m_new);
      l_run *= alpha;
#pragma unroll
      for (int ct = 0; ct < 4; ct++)
#pragma unroll
        for (int r = 0; r < 16; r++) oacc[ct][r] *= alpha;
      m_run = m_new;
    }
    float psum = 0.f;
#pragma unroll
    for (int r = 0; r < 16; r++) { sa[r] = exp2f(sa[r] - m_run); psum += sa[r]; }
    psum += __shfl_xor(psum, 32, 64);
    l_run += psum;

    // ---- build PV B-fragments in-register (pack + permlane32_swap) ----
    uint32_t pk[8];
#pragma unroll
    for (int g = 0; g < 8; ++g) {
      PKU pu; pu.h[0] = (f16)sa[2 * g]; pu.h[1] = (f16)sa[2 * g + 1];
      pk[g] = pu.u;
    }
    {
      int2v r0 = __builtin_amdgcn_permlane32_swap((int)pk[0], (int)pk[2], false, false);
      pk[0] = (uint32_t)r0.x; pk[2] = (uint32_t)r0.y;
      int2v r1 = __builtin_amdgcn_permlane32_swap((int)pk[1], (int)pk[3], false, false);
      pk[1] = (uint32_t)r1.x; pk[3] = (uint32_t)r1.y;
      int2v r2 = __builtin_amdgcn_permlane32_swap((int)pk[4], (int)pk[6], false, false);
      pk[4] = (uint32_t)r2.x; pk[6] = (uint32_t)r2.y;
      int2v r3 = __builtin_amdgcn_permlane32_swap((int)pk[5], (int)pk[7], false, false);
      pk[5] = (uint32_t)r3.x; pk[7] = (uint32_t)r3.y;
    }
    BFU b0f, b1f;
    b0f.u[0] = pk[0]; b0f.u[1] = pk[1]; b0f.u[2] = pk[2]; b0f.u[3] = pk[3];
    b1f.u[0] = pk[4]; b1f.u[1] = pk[5]; b1f.u[2] = pk[6]; b1f.u[3] = pk[7];

    // ---- PV: out^T = CW^T(A) . P^T(B), 2 ksteps (reads cc) ----
#pragma unroll
    for (int ks = 0; ks < 2; ++ks) {
      half8 bfh = ks ? b1f.h : b0f.h;
#pragma unroll
      for (int ct = 0; ct < 4; ct++) {
        H8 af;
        const uint64_t* pa = (const uint64_t*)(cc + (ct * 32 + l31) * CROW + ks * 16 + lhi * 8);
        af.q[0] = pa[0]; af.q[1] = pa[1];
        oacc[ct] = __builtin_amdgcn_mfma_f32_32x32x16_f16(af.h, bfh, oacc[ct], 0, 0, 0);
      }
    }

    // ---- commit CWT tile i+1 into cn ----
    if (pre) {
      uint64_t* e0 = (uint64_t*)(cn + cA * CROW + cch * 8);
      e0[0] = c0.q[0]; e0[1] = c0.q[1];
      uint64_t* e1 = (uint64_t*)(cn + (64 + cA) * CROW + cch * 8);
      e1[0] = c1.q[0]; e1[1] = c1.q[1];
    }
    __syncthreads();   // cn visible for next PV; cc reads done before next commit
  };

  for (int it2 = 0; it2 < 64; ++it2) {
    step(kA, kB, cbuf0, cbuf1, 2 * it2);
    step(kB, kA, cbuf1, cbuf0, 2 * it2 + 1);
  }

  // ---- epilogue: two q-halves through LDS, coalesced fp32 stores ----
  float inv = 1.0f / l_run;
  float* outp = out + ((size_t)(b * HQ_N + h) * QL_N + qt * 128) * DH_N;
#pragma unroll
  for (int p = 0; p < 2; ++p) {
    __syncthreads();
    if ((qloc >> 6) == p) {
      int lr = qloc & 63;
#pragma unroll
      for (int ct = 0; ct < 4; ct++)
#pragma unroll
        for (int r = 0; r < 16; r++) {
          int c = ct * 32 + (r & 3) + 8 * (r >> 2) + 4 * lhi;
          ot[lr * 133 + c] = oacc[ct][r] * inv;
        }
    }
    __syncthreads();
#pragma unroll
    for (int i = 0; i < 8; i++) {
      int flat = i * 256 + t; int q = flat >> 5, ch = flat & 31;
      float4 v;
      v.x = ot[q * 133 + ch * 4 + 0];
      v.y = ot[q * 133 + ch * 4 + 1];
      v.z = ot[q * 133 + ch * 4 + 2];
      v.w = ot[q * 133 + ch * 4 + 3];
      *(float4*)(outp + (size_t)(p * 64 + q) * DH_N + ch * 4) = v;
    }
  }
}

// ---------------------------------------------------------------------------
extern "C" void kernel_launch(void* const* d_in, const int* in_sizes, int n_in,
                              void* d_out, int out_size, void* d_ws, size_t ws_size,
                              hipStream_t stream) {
  (void)in_sizes; (void)n_in; (void)out_size; (void)ws_size;
  const float* Q   = (const float*)d_in[0];
  const float* C   = (const float*)d_in[1];
  const float* Kr  = (const float*)d_in[2];
  const float* Ul  = (const float*)d_in[3];
  const float* WUK = (const float*)d_in[4];
  const float* WUV = (const float*)d_in[5];
  float* out = (float*)d_out;
  char* ws = (char*)d_ws;
  // workspace carve (~37 MB)
  f16* Qeff2 = (f16*)ws;                   // 16777216 B
  f16* Cf    = (f16*)(ws + 16777216);      //  8388608 B
  f16* Krf   = (f16*)(ws + 25165824);      //  8388608 B
  f16* CWT   = (f16*)(ws + 33554432);      //  2097152 B
  f16* Kn    = (f16*)(ws + 35651584);      //  1048576 B
  f16* M2T2  = (f16*)(ws + 36700160);      //    32768 B
  f16* WUKh  = (f16*)(ws + 36732928);      //    65536 B
  f16* WUVT  = (f16*)(ws + 36798464);      //   131072 B

  hipLaunchKernelGGL(k_convert, dim3(4096), dim3(256), 0, stream, C, Kr, Cf, Krf);
  hipLaunchKernelGGL(k_weights, dim3(448),  dim3(256), 0, stream, Ul, WUK, WUV, M2T2, WUKh, WUVT);
  hipLaunchKernelGGL(k_qeff,    dim3(512),  dim3(256), 0, stream, Q, M2T2, Qeff2);
  hipLaunchKernelGGL(k_kn,      dim3(64),   dim3(256), 0, stream, Cf, WUKh, Kn);
  hipLaunchKernelGGL(k_cw,      dim3(256),  dim3(256), 0, stream, Cf, WUVT, CWT);
  hipLaunchKernelGGL(k_flash,   dim3(512),  dim3(256), 0, stream, Qeff2, Kn, Krf, CWT, out);
}

// Round 4
// 338.501 us; speedup vs baseline: 1.1896x; 1.1896x over previous
//
#include <hip/hip_runtime.h>
#include <stdint.h>

// ---- problem constants ----
#define B_N   2
#define HQ_N  32
#define HKV_N 8
#define QL_N  1024
#define SL_N  4096
#define DH_N  128
#define ROPE_N 64
#define RANK_N 512

typedef _Float16 f16;
typedef _Float16 half8 __attribute__((ext_vector_type(8)));
typedef float floatx16 __attribute__((ext_vector_type(16)));
typedef int int2v __attribute__((ext_vector_type(2)));

union H8 { half8 h; uint64_t q[2]; };
union PKU { f16 h[2]; uint32_t u; };
union BFU { uint32_t u[4]; half8 h; };

__device__ inline half8 cvt8(float4 a, float4 b) {
  half8 o;
  o[0] = (f16)a.x; o[1] = (f16)a.y; o[2] = (f16)a.z; o[3] = (f16)a.w;
  o[4] = (f16)b.x; o[5] = (f16)b.y; o[6] = (f16)b.z; o[7] = (f16)b.w;
  return o;
}

// ---------------------------------------------------------------------------
// prep 1: fp32 -> fp16 convert of K_rope_t2 only (C is consumed in f32 by
// k_kncw; flash reads Kn/CWT, never C).  grid = 2048.
// ---------------------------------------------------------------------------
__global__ __launch_bounds__(256) void k_convert(const float* __restrict__ Kr,
                                                 f16* __restrict__ Krf) {
  size_t idx = ((size_t)blockIdx.x * 256 + threadIdx.x) * 8;  // 4194304 f32
  float4 a = *(const float4*)(Kr + idx);
  float4 b = *(const float4*)(Kr + idx + 4);
  *(half8*)(Krf + idx) = cvt8(a, b);
}

// ---------------------------------------------------------------------------
// prep 2: weights: M2T2 (rotation), WUKh = f16(WUK), WUVT = f16(WUV^T).
// grid = 448 (16384 + 32768 + 65536 elements).
// ---------------------------------------------------------------------------
__global__ __launch_bounds__(256) void k_weights(const float* __restrict__ Ul,
                                                 const float* __restrict__ WUK,
                                                 const float* __restrict__ WUV,
                                                 f16* __restrict__ M2T2,
                                                 f16* __restrict__ WUKh,
                                                 f16* __restrict__ WUVT) {
  int idx = blockIdx.x * 256 + threadIdx.x;
  if (idx < 16384) {
    int c = idx >> 7, d = idx & 127;
    float v = 0.f;
    if (c < 64) { if (d >= 64) v = Ul[c * 64 + (d - 64)]; }
    else        { if (d < 64)  v = Ul[(c - 64) * 64 + d]; }
    M2T2[idx] = (f16)v;
  } else if (idx < 49152) {
    int i = idx - 16384;             // 64*512 flat copy-convert
    WUKh[i] = (f16)WUK[i];
  } else {
    int i = idx - 49152;             // WUVT[c][r] = WUV[r][c]
    int c = i >> 9, r = i & 511;
    WUVT[i] = (f16)WUV[r * 128 + c];
  }
}

// ---------------------------------------------------------------------------
// prep 3: Qeff2 = (f16(Q) @ M2n) * log2(e), LDS-free MFMA.  M=65536, K=N=128.
// A-frags = per-lane contiguous Q-row chunks (f32->f16 in reg); direct
// accumulator stores (32-lane 64B runs).  grid = 512, wave-split q.
// ---------------------------------------------------------------------------
__global__ __launch_bounds__(256) void k_qeff(const float* __restrict__ Q,
                                              const f16* __restrict__ M2T2,
                                              f16* __restrict__ Qeff2) {
  int t = threadIdx.x;
  int wave = t >> 6, lane = t & 63, l31 = lane & 31, lhi = lane >> 5;
  size_t q0 = (size_t)blockIdx.x * 128 + wave * 32;
  const float* qp = Q + (q0 + l31) * DH_N + lhi * 8;
  floatx16 acc[4];
#pragma unroll
  for (int ct = 0; ct < 4; ct++)
#pragma unroll
    for (int r = 0; r < 16; r++) acc[ct][r] = 0.f;
#pragma unroll
  for (int kk = 0; kk < 8; ++kk) {
    float4 a = *(const float4*)(qp + kk * 16);
    float4 b = *(const float4*)(qp + kk * 16 + 4);
    half8 af = cvt8(a, b);
#pragma unroll
    for (int ct = 0; ct < 4; ct++) {
      half8 bf = *(const half8*)(M2T2 + (size_t)(ct * 32 + l31) * 128 + kk * 16 + lhi * 8);
      acc[ct] = __builtin_amdgcn_mfma_f32_32x32x16_f16(af, bf, acc[ct], 0, 0, 0);
    }
  }
  const float LOG2E = 1.44269504f;
#pragma unroll
  for (int ct = 0; ct < 4; ct++)
#pragma unroll
    for (int r = 0; r < 16; r++) {
      int row = (r & 3) + 8 * (r >> 2) + 4 * lhi;
      Qeff2[(q0 + row) * 128 + ct * 32 + l31] = (f16)(acc[ct][r] * LOG2E);
    }
}

// ---------------------------------------------------------------------------
// prep 4 (fused): Kn[b][s][64] = C@WUK^T  AND  CWT[b][c][s] = (C@WUV)^T.
// Key: the per-lane C-row fragment cf = C[s0+l31][kchunk] serves as BOTH the
// A-operand of Kn (rows=s) and the B-operand of CWT^T = WUVT(A,rows=c) x
// C^T(B,cols=s).  Zero LDS; all stores are 32-lane 64B runs.
// grid = 64 = b(2) x 32 s-supertiles(128); wave-split 32 s each.
// ---------------------------------------------------------------------------
__global__ __launch_bounds__(256) void k_kncw(const float* __restrict__ C,
                                              const f16* __restrict__ WUKh,
                                              const f16* __restrict__ WUVT,
                                              f16* __restrict__ Kn,
                                              f16* __restrict__ CWT) {
  int t = threadIdx.x;
  int wave = t >> 6, lane = t & 63, l31 = lane & 31, lhi = lane >> 5;
  int b = blockIdx.x >> 5, st = blockIdx.x & 31;
  int s0 = st * 128 + wave * 32;
  const float* cp = C + ((size_t)b * SL_N + s0 + l31) * RANK_N + lhi * 8;
  floatx16 akn[2], acw[4];
#pragma unroll
  for (int ct = 0; ct < 2; ct++)
#pragma unroll
    for (int r = 0; r < 16; r++) akn[ct][r] = 0.f;
#pragma unroll
  for (int ct = 0; ct < 4; ct++)
#pragma unroll
    for (int r = 0; r < 16; r++) acw[ct][r] = 0.f;
#pragma unroll 4
  for (int kk = 0; kk < 32; ++kk) {
    float4 a = *(const float4*)(cp + kk * 16);
    float4 bq = *(const float4*)(cp + kk * 16 + 4);
    half8 cf = cvt8(a, bq);
#pragma unroll
    for (int ct = 0; ct < 2; ct++) {
      half8 bf = *(const half8*)(WUKh + (size_t)(ct * 32 + l31) * RANK_N + kk * 16 + lhi * 8);
      akn[ct] = __builtin_amdgcn_mfma_f32_32x32x16_f16(cf, bf, akn[ct], 0, 0, 0);
    }
#pragma unroll
    for (int ct = 0; ct < 4; ct++) {
      half8 af = *(const half8*)(WUVT + (size_t)(ct * 32 + l31) * RANK_N + kk * 16 + lhi * 8);
      acw[ct] = __builtin_amdgcn_mfma_f32_32x32x16_f16(af, cf, acw[ct], 0, 0, 0);
    }
  }
#pragma unroll
  for (int ct = 0; ct < 2; ct++)
#pragma unroll
    for (int r = 0; r < 16; r++) {
      int row = (r & 3) + 8 * (r >> 2) + 4 * lhi;     // s-local
      Kn[((size_t)b * SL_N + s0 + row) * 64 + ct * 32 + l31] = (f16)akn[ct][r];
    }
#pragma unroll
  for (int ct = 0; ct < 4; ct++)
#pragma unroll
    for (int r = 0; r < 16; r++) {
      int row = (r & 3) + 8 * (r >> 2) + 4 * lhi;     // c-local
      CWT[((size_t)b * DH_N + ct * 32 + row) * SL_N + s0 + l31] = (f16)acw[ct][r];
    }
}

// ---------------------------------------------------------------------------
// flash kernel: round-2 staging structure (block-unique reg->LDS commits,
// 2 barriers), s-tile 64 (half the barriers/softmax passes of round 2),
// base-2 softmax, in-register P (pack+permlane32_swap), XOR-swizzled cbuf.
// LDS 50.5 KB.  grid = 512 = (b, h, q-tile 128).
// ---------------------------------------------------------------------------
#define KROW 132   // 64 rows; stride 66 dw == 2 mod 32 -> 2-way (free)
#define CROW 68    // 128 rows; stride 34 dw == 2 mod 32; chunk XOR-swizzled

__global__ __launch_bounds__(256, 2) void k_flash(
    const f16* __restrict__ Qeff2, const f16* __restrict__ Kn,
    const f16* __restrict__ Krf, const f16* __restrict__ CWT,
    float* __restrict__ out) {
  __shared__ __align__(16) char smem[51712];
  f16* kbuf  = (f16*)smem;                    // [64][132] 16896 B (0..63 Kn, 64..127 rope)
  f16* cbuf0 = (f16*)(smem + 16896);          // [128][68] 17408 B
  f16* cbuf1 = (f16*)(smem + 34304);
  float* ot  = (float*)smem;                  // epilogue [64][133] 34048 B

  int t = threadIdx.x;
  int wave = t >> 6, lane = t & 63, l31 = lane & 31, lhi = lane >> 5;
  int qt = blockIdx.x & 7; int h = (blockIdx.x >> 3) & 31; int b = blockIdx.x >> 8;
  int kv = h >> 2;
  int qloc = wave * 32 + l31;

  const f16* Knb = Kn + (size_t)b * SL_N * 64;
  const f16* Kb  = Krf + (size_t)(b * HKV_N + kv) * SL_N * ROPE_N;
  const f16* Wb  = CWT + (size_t)b * DH_N * SL_N;

  // persistent Q fragments (B-operand), K = 128, pre-scaled by log2e
  half8 qf[8];
  {
    const f16* qrow = Qeff2 + ((size_t)(b * HQ_N + h) * QL_N + qt * 128 + qloc) * 128 + lhi * 8;
#pragma unroll
    for (int kk = 0; kk < 8; kk++) qf[kk] = *(const half8*)(qrow + kk * 16);
  }

  floatx16 oacc[4];
#pragma unroll
  for (int ct = 0; ct < 4; ct++)
#pragma unroll
    for (int r = 0; r < 16; r++) oacc[ct][r] = 0.f;
  float m_run = -1e30f, l_run = 0.f;

  // staging maps (block-unique, coalesced 64-128B runs):
  int kr = t >> 3, kc = t & 7;    // K: rows kr, kr+32; 16B chunk kc
  int cA = t >> 2, cch = t & 3;   // CWT: rows cA, 64+cA; chunks cch, cch+4
  const f16* pKn = Knb + (size_t)kr * 64 + kc * 8;
  const f16* pKr = Kb + (size_t)kr * ROPE_N + kc * 8;
  const f16* pW0 = Wb + (size_t)cA * SL_N;
  const f16* pW1 = Wb + (size_t)(64 + cA) * SL_N;
  // XOR chunk swizzle (write side): same XOR used on PV read side
  int sw0 = ((cch) ^ (cA & 7)) * 8;
  int sw1 = ((cch + 4) ^ (cA & 7)) * 8;
  int rsw = l31 & 7;              // read-side row key

  // ---- preload tile 0 ----
  {
    H8 a0, a1, r0, r1, c0, c1, c2, c3;
    a0.h = *(const half8*)(pKn);
    a1.h = *(const half8*)(pKn + 32 * 64);
    r0.h = *(const half8*)(pKr);
    r1.h = *(const half8*)(pKr + 32 * ROPE_N);
    c0.h = *(const half8*)(pW0 + cch * 8);
    c1.h = *(const half8*)(pW0 + (cch + 4) * 8);
    c2.h = *(const half8*)(pW1 + cch * 8);
    c3.h = *(const half8*)(pW1 + (cch + 4) * 8);
    uint64_t* d;
    d = (uint64_t*)(kbuf + kr * KROW + kc * 8);              d[0] = a0.q[0]; d[1] = a0.q[1];
    d = (uint64_t*)(kbuf + (kr + 32) * KROW + kc * 8);       d[0] = a1.q[0]; d[1] = a1.q[1];
    d = (uint64_t*)(kbuf + kr * KROW + 64 + kc * 8);         d[0] = r0.q[0]; d[1] = r0.q[1];
    d = (uint64_t*)(kbuf + (kr + 32) * KROW + 64 + kc * 8);  d[0] = r1.q[0]; d[1] = r1.q[1];
    d = (uint64_t*)(cbuf0 + cA * CROW + sw0);                d[0] = c0.q[0]; d[1] = c0.q[1];
    d = (uint64_t*)(cbuf0 + cA * CROW + sw1);                d[0] = c1.q[0]; d[1] = c1.q[1];
    d = (uint64_t*)(cbuf0 + (64 + cA) * CROW + sw0);         d[0] = c2.q[0]; d[1] = c2.q[1];
    d = (uint64_t*)(cbuf0 + (64 + cA) * CROW + sw1);         d[0] = c3.q[0]; d[1] = c3.q[1];
  }
  __syncthreads();

  for (int it = 0; it < 64; ++it) {
    f16* cc = (it & 1) ? cbuf1 : cbuf0;
    f16* cn = (it & 1) ? cbuf0 : cbuf1;
    bool pre = it < 63;
    int s0n = (it + 1) * 64;
    H8 a0, a1, r0, r1, c0, c1, c2, c3;
    if (pre) {  // issue next-tile loads (in flight across S^T)
      size_t ko = (size_t)s0n * 64;
      a0.h = *(const half8*)(pKn + ko);
      a1.h = *(const half8*)(pKn + ko + 32 * 64);
      r0.h = *(const half8*)(pKr + ko);
      r1.h = *(const half8*)(pKr + ko + 32 * ROPE_N);
      c0.h = *(const half8*)(pW0 + s0n + cch * 8);
      c1.h = *(const half8*)(pW0 + s0n + (cch + 4) * 8);
      c2.h = *(const half8*)(pW1 + s0n + cch * 8);
      c3.h = *(const half8*)(pW1 + s0n + (cch + 4) * 8);
    }

    // ---- S^T = K_eff(A) . Q^T(B), K=128, two 32-s blocks ----
    floatx16 sa0, sa1;
#pragma unroll
    for (int r = 0; r < 16; r++) { sa0[r] = 0.f; sa1[r] = 0.f; }
    const f16* ka0 = kbuf + l31 * KROW + lhi * 8;
    const f16* ka1 = kbuf + (32 + l31) * KROW + lhi * 8;
#pragma unroll
    for (int kk = 0; kk < 8; kk++) {
      H8 x0, x1;
      const uint64_t* p0 = (const uint64_t*)(ka0 + kk * 16);
      const uint64_t* p1 = (const uint64_t*)(ka1 + kk * 16);
      x0.q[0] = p0[0]; x0.q[1] = p0[1];
      x1.q[0] = p1[0]; x1.q[1] = p1[1];
      sa0 = __builtin_amdgcn_mfma_f32_32x32x16_f16(x0.h, qf[kk], sa0, 0, 0, 0);
      sa1 = __builtin_amdgcn_mfma_f32_32x32x16_f16(x1.h, qf[kk], sa1, 0, 0, 0);
    }
    __syncthreads();   // barrier A: kbuf reads done

    // ---- commit staged tile i+1 (overlaps softmax VALU; LDS pipe idle here) ----
    if (pre) {
      uint64_t* d;
      d = (uint64_t*)(kbuf + kr * KROW + kc * 8);              d[0] = a0.q[0]; d[1] = a0.q[1];
      d = (uint64_t*)(kbuf + (kr + 32) * KROW + kc * 8);       d[0] = a1.q[0]; d[1] = a1.q[1];
      d = (uint64_t*)(kbuf + kr * KROW + 64 + kc * 8);         d[0] = r0.q[0]; d[1] = r0.q[1];
      d = (uint64_t*)(kbuf + (kr + 32) * KROW + 64 + kc * 8);  d[0] = r1.q[0]; d[1] = r1.q[1];
      d = (uint64_t*)(cn + cA * CROW + sw0);                   d[0] = c0.q[0]; d[1] = c0.q[1];
      d = (uint64_t*)(cn + cA * CROW + sw1);                   d[0] = c1.q[0]; d[1] = c1.q[1];
      d = (uint64_t*)(cn + (64 + cA) * CROW + sw0);            d[0] = c2.q[0]; d[1] = c2.q[1];
      d = (uint64_t*)(cn + (64 + cA) * CROW + sw1);            d[0] = c3.q[0]; d[1] = c3.q[1];
    }

    // ---- online softmax, base-2, over 64 s (q in lane + partner xor32) ----
    float mt = -1e30f;
#pragma unroll
    for (int r = 0; r < 16; r++) { mt = fmaxf(mt, sa0[r]); mt = fmaxf(mt, sa1[r]); }
    mt = fmaxf(mt, __shfl_xor(mt, 32, 64));
    if (__any(mt > m_run)) {   // strict defer-rescale (exact)
      float m_new = fmaxf(m_run, mt);
      float alpha = exp2f(m_run - m_new);
      l_run *= alpha;
#pragma unroll
      for (int ct = 0; ct < 4; ct++)
#pragma unroll
        for (int r = 0; r < 16; r++) oacc[ct][r] *= alpha;
      m_run = m_new;
    }
    float psum = 0.f;
#pragma unroll
    for (int r = 0; r < 16; r++) { sa0[r] = exp2f(sa0[r] - m_run); psum += sa0[r]; }
#pragma unroll
    for (int r = 0; r < 16; r++) { sa1[r] = exp2f(sa1[r] - m_run); psum += sa1[r]; }
    psum += __shfl_xor(psum, 32, 64);
    l_run += psum;

    // ---- build 4 PV B-fragments in-register (pack + permlane32_swap) ----
    half8 bfr0, bfr1, bfr2, bfr3;
    {
      uint32_t pk[8];
#pragma unroll
      for (int g = 0; g < 8; ++g) {
        PKU pu; pu.h[0] = (f16)sa0[2 * g]; pu.h[1] = (f16)sa0[2 * g + 1];
        pk[g] = pu.u;
      }
      int2v r0v = __builtin_amdgcn_permlane32_swap((int)pk[0], (int)pk[2], false, false);
      pk[0] = (uint32_t)r0v.x; pk[2] = (uint32_t)r0v.y;
      int2v r1v = __builtin_amdgcn_permlane32_swap((int)pk[1], (int)pk[3], false, false);
      pk[1] = (uint32_t)r1v.x; pk[3] = (uint32_t)r1v.y;
      int2v r2v = __builtin_amdgcn_permlane32_swap((int)pk[4], (int)pk[6], false, false);
      pk[4] = (uint32_t)r2v.x; pk[6] = (uint32_t)r2v.y;
      int2v r3v = __builtin_amdgcn_permlane32_swap((int)pk[5], (int)pk[7], false, false);
      pk[5] = (uint32_t)r3v.x; pk[7] = (uint32_t)r3v.y;
      BFU f0, f1;
      f0.u[0] = pk[0]; f0.u[1] = pk[1]; f0.u[2] = pk[2]; f0.u[3] = pk[3];
      f1.u[0] = pk[4]; f1.u[1] = pk[5]; f1.u[2] = pk[6]; f1.u[3] = pk[7];
      bfr0 = f0.h; bfr1 = f1.h;
    }
    {
      uint32_t pk[8];
#pragma unroll
      for (int g = 0; g < 8; ++g) {
        PKU pu; pu.h[0] = (f16)sa1[2 * g]; pu.h[1] = (f16)sa1[2 * g + 1];
        pk[g] = pu.u;
      }
      int2v r0v = __builtin_amdgcn_permlane32_swap((int)pk[0], (int)pk[2], false, false);
      pk[0] = (uint32_t)r0v.x; pk[2] = (uint32_t)r0v.y;
      int2v r1v = __builtin_amdgcn_permlane32_swap((int)pk[1], (int)pk[3], false, false);
      pk[1] = (uint32_t)r1v.x; pk[3] = (uint32_t)r1v.y;
      int2v r2v = __builtin_amdgcn_permlane32_swap((int)pk[4], (int)pk[6], false, false);
      pk[4] = (uint32_t)r2v.x; pk[6] = (uint32_t)r2v.y;
      int2v r3v = __builtin_amdgcn_permlane32_swap((int)pk[5], (int)pk[7], false, false);
      pk[5] = (uint32_t)r3v.x; pk[7] = (uint32_t)r3v.y;
      BFU f0, f1;
      f0.u[0] = pk[0]; f0.u[1] = pk[1]; f0.u[2] = pk[2]; f0.u[3] = pk[3];
      f1.u[0] = pk[4]; f1.u[1] = pk[5]; f1.u[2] = pk[6]; f1.u[3] = pk[7];
      bfr2 = f0.h; bfr3 = f1.h;
    }

    // ---- PV: out^T = CW^T(A) . P^T(B), 4 ksteps (swizzled cc reads) ----
#pragma unroll
    for (int ks = 0; ks < 4; ++ks) {
      half8 bfh = (ks == 0) ? bfr0 : (ks == 1) ? bfr1 : (ks == 2) ? bfr2 : bfr3;
#pragma unroll
      for (int ct = 0; ct < 4; ct++) {
        H8 af;
        const uint64_t* pa = (const uint64_t*)(cc + (ct * 32 + l31) * CROW +
                                               (((ks * 2 + lhi) ^ rsw) * 8));
        af.q[0] = pa[0]; af.q[1] = pa[1];
        oacc[ct] = __builtin_amdgcn_mfma_f32_32x32x16_f16(af.h, bfh, oacc[ct], 0, 0, 0);
      }
    }
    __syncthreads();   // barrier B: commits visible for next S^T / PV
  }

  // ---- epilogue: two q-halves through LDS, coalesced fp32 stores ----
  float inv = 1.0f / l_run;
  float* outp = out + ((size_t)(b * HQ_N + h) * QL_N + qt * 128) * DH_N;
#pragma unroll
  for (int p = 0; p < 2; ++p) {
    __syncthreads();
    if ((qloc >> 6) == p) {
      int lr = qloc & 63;
#pragma unroll
      for (int ct = 0; ct < 4; ct++)
#pragma unroll
        for (int r = 0; r < 16; r++) {
          int c = ct * 32 + (r & 3) + 8 * (r >> 2) + 4 * lhi;
          ot[lr * 133 + c] = oacc[ct][r] * inv;
        }
    }
    __syncthreads();
#pragma unroll
    for (int i = 0; i < 8; i++) {
      int flat = i * 256 + t; int q = flat >> 5, ch = flat & 31;
      float4 v;
      v.x = ot[q * 133 + ch * 4 + 0];
      v.y = ot[q * 133 + ch * 4 + 1];
      v.z = ot[q * 133 + ch * 4 + 2];
      v.w = ot[q * 133 + ch * 4 + 3];
      *(float4*)(outp + (size_t)(p * 64 + q) * DH_N + ch * 4) = v;
    }
  }
}

// ---------------------------------------------------------------------------
extern "C" void kernel_launch(void* const* d_in, const int* in_sizes, int n_in,
                              void* d_out, int out_size, void* d_ws, size_t ws_size,
                              hipStream_t stream) {
  (void)in_sizes; (void)n_in; (void)out_size; (void)ws_size;
  const float* Q   = (const float*)d_in[0];
  const float* C   = (const float*)d_in[1];
  const float* Kr  = (const float*)d_in[2];
  const float* Ul  = (const float*)d_in[3];
  const float* WUK = (const float*)d_in[4];
  const float* WUV = (const float*)d_in[5];
  float* out = (float*)d_out;
  char* ws = (char*)d_ws;
  // workspace carve (~28.5 MB)
  f16* Qeff2 = (f16*)ws;                   // 16777216 B
  f16* Krf   = (f16*)(ws + 16777216);      //  8388608 B
  f16* CWT   = (f16*)(ws + 25165824);      //  2097152 B
  f16* Kn    = (f16*)(ws + 27262976);      //  1048576 B
  f16* M2T2  = (f16*)(ws + 28311552);      //    32768 B
  f16* WUKh  = (f16*)(ws + 28344320);      //    65536 B
  f16* WUVT  = (f16*)(ws + 28409856);      //   131072 B

  hipLaunchKernelGGL(k_convert, dim3(2048), dim3(256), 0, stream, Kr, Krf);
  hipLaunchKernelGGL(k_weights, dim3(448),  dim3(256), 0, stream, Ul, WUK, WUV, M2T2, WUKh, WUVT);
  hipLaunchKernelGGL(k_qeff,    dim3(512),  dim3(256), 0, stream, Q, M2T2, Qeff2);
  hipLaunchKernelGGL(k_kncw,    dim3(64),   dim3(256), 0, stream, C, WUKh, WUVT, Kn, CWT);
  hipLaunchKernelGGL(k_flash,   dim3(512),  dim3(256), 0, stream, Qeff2, Kn, Krf, CWT, out);
}

// Round 6
// 287.688 us; speedup vs baseline: 1.3997x; 1.1766x over previous
//
#include <hip/hip_runtime.h>
#include <stdint.h>

// ---- problem constants ----
#define B_N   2
#define HQ_N  32
#define HKV_N 8
#define QL_N  1024
#define SL_N  4096
#define DH_N  128
#define ROPE_N 64
#define RANK_N 512

typedef _Float16 f16;
typedef _Float16 half8 __attribute__((ext_vector_type(8)));
typedef __fp16 fp16x2 __attribute__((ext_vector_type(2)));
typedef float floatx16 __attribute__((ext_vector_type(16)));
typedef int int2v __attribute__((ext_vector_type(2)));

union H8 { half8 h; uint64_t q[2]; };
union PK2 { fp16x2 h; uint32_t u; };
union BFU { uint32_t u[4]; half8 h; };

__device__ inline half8 cvt8(float4 a, float4 b) {
  half8 o;
  o[0] = (f16)a.x; o[1] = (f16)a.y; o[2] = (f16)a.z; o[3] = (f16)a.w;
  o[4] = (f16)b.x; o[5] = (f16)b.y; o[6] = (f16)b.z; o[7] = (f16)b.w;
  return o;
}

// ---------------------------------------------------------------------------
// prep 1: fp32 -> fp16 convert of K_rope_t2 only.  grid = 2048.
// ---------------------------------------------------------------------------
__global__ __launch_bounds__(256) void k_convert(const float* __restrict__ Kr,
                                                 f16* __restrict__ Krf) {
  size_t idx = ((size_t)blockIdx.x * 256 + threadIdx.x) * 8;  // 4194304 f32
  float4 a = *(const float4*)(Kr + idx);
  float4 b = *(const float4*)(Kr + idx + 4);
  *(half8*)(Krf + idx) = cvt8(a, b);
}

// ---------------------------------------------------------------------------
// prep 2: weights: M2T2 (rotation), WUKh = f16(WUK), WUVT = f16(WUV^T).
// grid = 448 (16384 + 32768 + 65536 elements).
// ---------------------------------------------------------------------------
__global__ __launch_bounds__(256) void k_weights(const float* __restrict__ Ul,
                                                 const float* __restrict__ WUK,
                                                 const float* __restrict__ WUV,
                                                 f16* __restrict__ M2T2,
                                                 f16* __restrict__ WUKh,
                                                 f16* __restrict__ WUVT) {
  int idx = blockIdx.x * 256 + threadIdx.x;
  if (idx < 16384) {
    int c = idx >> 7, d = idx & 127;
    float v = 0.f;
    if (c < 64) { if (d >= 64) v = Ul[c * 64 + (d - 64)]; }
    else        { if (d < 64)  v = Ul[(c - 64) * 64 + d]; }
    M2T2[idx] = (f16)v;
  } else if (idx < 49152) {
    int i = idx - 16384;             // 64*512 flat copy-convert
    WUKh[i] = (f16)WUK[i];
  } else {
    int i = idx - 49152;             // WUVT[c][r] = WUV[r][c]
    int c = i >> 9, r = i & 511;
    WUVT[i] = (f16)WUV[r * 128 + c];
  }
}

// ---------------------------------------------------------------------------
// prep 3 (fused): Kn[b][s][64] = C@WUK^T  AND  CWT[b][c][s] = (C@WUV)^T.
// grid = 256 = b(2) x 128 s-tiles(32); the 6 output MFMA-chains are split
// across the 4 waves (wave-uniform branches); each wave re-reads the shared
// per-lane C-row fragment through L1.  Zero LDS.
// ---------------------------------------------------------------------------
__global__ __launch_bounds__(256) void k_kncw(const float* __restrict__ C,
                                              const f16* __restrict__ WUKh,
                                              const f16* __restrict__ WUVT,
                                              f16* __restrict__ Kn,
                                              f16* __restrict__ CWT) {
  int t = threadIdx.x;
  int wave = t >> 6, lane = t & 63, l31 = lane & 31, lhi = lane >> 5;
  int b = blockIdx.x >> 7, st = blockIdx.x & 127;
  int s0 = st * 32;
  const float* cp = C + ((size_t)b * SL_N + s0 + l31) * RANK_N + lhi * 8;
  floatx16 a0, a1;
#pragma unroll
  for (int r = 0; r < 16; r++) { a0[r] = 0.f; a1[r] = 0.f; }
  // chain assignment: w0: Kn ct0+ct1 | w1: CWT ct0 | w2: CWT ct1+ct2 | w3: CWT ct3
#pragma unroll 4
  for (int kk = 0; kk < 32; ++kk) {
    float4 fa = *(const float4*)(cp + kk * 16);
    float4 fb = *(const float4*)(cp + kk * 16 + 4);
    half8 cf = cvt8(fa, fb);
    if (wave == 0) {
      half8 b0 = *(const half8*)(WUKh + (size_t)l31 * RANK_N + kk * 16 + lhi * 8);
      half8 b1 = *(const half8*)(WUKh + (size_t)(32 + l31) * RANK_N + kk * 16 + lhi * 8);
      a0 = __builtin_amdgcn_mfma_f32_32x32x16_f16(cf, b0, a0, 0, 0, 0);
      a1 = __builtin_amdgcn_mfma_f32_32x32x16_f16(cf, b1, a1, 0, 0, 0);
    } else if (wave == 1) {
      half8 w0 = *(const half8*)(WUVT + (size_t)l31 * RANK_N + kk * 16 + lhi * 8);
      a0 = __builtin_amdgcn_mfma_f32_32x32x16_f16(w0, cf, a0, 0, 0, 0);
    } else if (wave == 2) {
      half8 w1 = *(const half8*)(WUVT + (size_t)(32 + l31) * RANK_N + kk * 16 + lhi * 8);
      half8 w2 = *(const half8*)(WUVT + (size_t)(64 + l31) * RANK_N + kk * 16 + lhi * 8);
      a0 = __builtin_amdgcn_mfma_f32_32x32x16_f16(w1, cf, a0, 0, 0, 0);
      a1 = __builtin_amdgcn_mfma_f32_32x32x16_f16(w2, cf, a1, 0, 0, 0);
    } else {
      half8 w3 = *(const half8*)(WUVT + (size_t)(96 + l31) * RANK_N + kk * 16 + lhi * 8);
      a0 = __builtin_amdgcn_mfma_f32_32x32x16_f16(w3, cf, a0, 0, 0, 0);
    }
  }
  if (wave == 0) {
#pragma unroll
    for (int r = 0; r < 16; r++) {
      int row = (r & 3) + 8 * (r >> 2) + 4 * lhi;     // s-local
      Kn[((size_t)b * SL_N + s0 + row) * 64 + l31]      = (f16)a0[r];
      Kn[((size_t)b * SL_N + s0 + row) * 64 + 32 + l31] = (f16)a1[r];
    }
  } else if (wave == 1) {
#pragma unroll
    for (int r = 0; r < 16; r++) {
      int row = (r & 3) + 8 * (r >> 2) + 4 * lhi;     // c-local
      CWT[((size_t)b * DH_N + row) * SL_N + s0 + l31] = (f16)a0[r];
    }
  } else if (wave == 2) {
#pragma unroll
    for (int r = 0; r < 16; r++) {
      int row = (r & 3) + 8 * (r >> 2) + 4 * lhi;
      CWT[((size_t)b * DH_N + 32 + row) * SL_N + s0 + l31] = (f16)a0[r];
      CWT[((size_t)b * DH_N + 64 + row) * SL_N + s0 + l31] = (f16)a1[r];
    }
  } else {
#pragma unroll
    for (int r = 0; r < 16; r++) {
      int row = (r & 3) + 8 * (r >> 2) + 4 * lhi;
      CWT[((size_t)b * DH_N + 96 + row) * SL_N + s0 + l31] = (f16)a0[r];
    }
  }
}

// ---------------------------------------------------------------------------
// flash kernel: fused Qeff prologue (Q @ M2n * log2e via MFMA + LDS
// transpose), 64-s tiles, 2 barriers/iter, commits AFTER PV (full-window
// load flight, round-2 proven), raw-exp2 + cvt_pkrtz softmax, setprio
// around MFMA clusters.  LDS 50.5 KB -> 2 blocks/CU.
// grid = 512 = (b, h, q-tile 128).
// ---------------------------------------------------------------------------
#define KROW 132   // 64 rows; stride 66 dw == 2 mod 32 -> 2-way (free)
#define CROW 68    // 128 rows; stride 34 dw == 2 mod 32; chunk XOR-swizzled

__global__ __launch_bounds__(256, 2) void k_flash(
    const float* __restrict__ Q, const f16* __restrict__ M2T2,
    const f16* __restrict__ Kn, const f16* __restrict__ Krf,
    const f16* __restrict__ CWT, float* __restrict__ out) {
  __shared__ __align__(16) char smem[51712];
  f16* kbuf  = (f16*)smem;                    // [64][132] 16896 B (0..63 Kn, 64..127 rope)
  f16* cbuf0 = (f16*)(smem + 16896);          // [128][68] 17408 B
  f16* cbuf1 = (f16*)(smem + 34304);
  f16* qs    = (f16*)smem;                    // prologue [128][132] 33792 B
  float* ot  = (float*)smem;                  // epilogue [64][133] 34048 B

  int t = threadIdx.x;
  int wave = t >> 6, lane = t & 63, l31 = lane & 31, lhi = lane >> 5;
  int qt = blockIdx.x & 7; int h = (blockIdx.x >> 3) & 31; int b = blockIdx.x >> 8;
  int kv = h >> 2;
  int qloc = wave * 32 + l31;

  const f16* Knb = Kn + (size_t)b * SL_N * 64;
  const f16* Kb  = Krf + (size_t)(b * HKV_N + kv) * SL_N * ROPE_N;
  const f16* Wb  = CWT + (size_t)b * DH_N * SL_N;

  // staging maps (block-unique, coalesced):
  int kr = t >> 3, kc = t & 7;    // K: rows kr, kr+32; 16B chunk kc
  int cA = t >> 2, cch = t & 3;   // CWT: rows cA, 64+cA; chunks cch, cch+4
  const f16* pKn = Knb + (size_t)kr * 64 + kc * 8;
  const f16* pKr = Kb + (size_t)kr * ROPE_N + kc * 8;
  const f16* pW0 = Wb + (size_t)cA * SL_N;
  const f16* pW1 = Wb + (size_t)(64 + cA) * SL_N;
  int sw0 = ((cch) ^ (cA & 7)) * 8;
  int sw1 = ((cch + 4) ^ (cA & 7)) * 8;
  int rsw = l31 & 7;              // read-side swizzle key

  // ---- issue tile-0 staging loads (land during the prologue) ----
  H8 a0, a1, r0, r1, c0, c1, c2, c3;
  a0.h = *(const half8*)(pKn);
  a1.h = *(const half8*)(pKn + 32 * 64);
  r0.h = *(const half8*)(pKr);
  r1.h = *(const half8*)(pKr + 32 * ROPE_N);
  c0.h = *(const half8*)(pW0 + cch * 8);
  c1.h = *(const half8*)(pW0 + (cch + 4) * 8);
  c2.h = *(const half8*)(pW1 + cch * 8);
  c3.h = *(const half8*)(pW1 + (cch + 4) * 8);

  // ---- fused Qeff prologue: qs[128][132] = (f16(Q) @ M2n) * log2e ----
  {
    const float* qp = Q + ((size_t)(b * HQ_N + h) * QL_N + qt * 128 + wave * 32 + l31) * DH_N + lhi * 8;
    floatx16 acc[4];
#pragma unroll
    for (int ct = 0; ct < 4; ct++)
#pragma unroll
      for (int r = 0; r < 16; r++) acc[ct][r] = 0.f;
#pragma unroll
    for (int kk = 0; kk < 8; ++kk) {
      float4 fa = *(const float4*)(qp + kk * 16);
      float4 fb = *(const float4*)(qp + kk * 16 + 4);
      half8 af = cvt8(fa, fb);
#pragma unroll
      for (int ct = 0; ct < 4; ct++) {
        half8 bf = *(const half8*)(M2T2 + (size_t)(ct * 32 + l31) * 128 + kk * 16 + lhi * 8);
        acc[ct] = __builtin_amdgcn_mfma_f32_32x32x16_f16(af, bf, acc[ct], 0, 0, 0);
      }
    }
    const float LOG2E = 1.44269504f;
#pragma unroll
    for (int ct = 0; ct < 4; ct++)
#pragma unroll
      for (int r = 0; r < 16; r++) {
        int row = (r & 3) + 8 * (r >> 2) + 4 * lhi;
        qs[(wave * 32 + row) * 132 + ct * 32 + l31] = (f16)(acc[ct][r] * LOG2E);
      }
  }
  __syncthreads();
  half8 qf[8];
#pragma unroll
  for (int kk = 0; kk < 8; kk++)
    qf[kk] = *(const half8*)(qs + (size_t)qloc * 132 + kk * 16 + lhi * 8);
  __syncthreads();   // qs reads done; smem now owned by kbuf/cbuf

  // ---- commit tile 0 ----
  {
    uint64_t* d;
    d = (uint64_t*)(kbuf + kr * KROW + kc * 8);              d[0] = a0.q[0]; d[1] = a0.q[1];
    d = (uint64_t*)(kbuf + (kr + 32) * KROW + kc * 8);       d[0] = a1.q[0]; d[1] = a1.q[1];
    d = (uint64_t*)(kbuf + kr * KROW + 64 + kc * 8);         d[0] = r0.q[0]; d[1] = r0.q[1];
    d = (uint64_t*)(kbuf + (kr + 32) * KROW + 64 + kc * 8);  d[0] = r1.q[0]; d[1] = r1.q[1];
    d = (uint64_t*)(cbuf0 + cA * CROW + sw0);                d[0] = c0.q[0]; d[1] = c0.q[1];
    d = (uint64_t*)(cbuf0 + cA * CROW + sw1);                d[0] = c1.q[0]; d[1] = c1.q[1];
    d = (uint64_t*)(cbuf0 + (64 + cA) * CROW + sw0);         d[0] = c2.q[0]; d[1] = c2.q[1];
    d = (uint64_t*)(cbuf0 + (64 + cA) * CROW + sw1);         d[0] = c3.q[0]; d[1] = c3.q[1];
  }
  __syncthreads();

  floatx16 oacc[4];
#pragma unroll
  for (int ct = 0; ct < 4; ct++)
#pragma unroll
    for (int r = 0; r < 16; r++) oacc[ct][r] = 0.f;
  float m_run = -1e30f, l_run = 0.f;

  for (int it = 0; it < 64; ++it) {
    f16* cc = (it & 1) ? cbuf1 : cbuf0;
    f16* cn = (it & 1) ? cbuf0 : cbuf1;
    bool pre = it < 63;
    int s0n = (it + 1) * 64;
    if (pre) {  // issue next-tile loads; commits AFTER PV (full-window flight)
      size_t ko = (size_t)s0n * 64;
      a0.h = *(const half8*)(pKn + ko);
      a1.h = *(const half8*)(pKn + ko + 32 * 64);
      r0.h = *(const half8*)(pKr + ko);
      r1.h = *(const half8*)(pKr + ko + 32 * ROPE_N);
      c0.h = *(const half8*)(pW0 + s0n + cch * 8);
      c1.h = *(const half8*)(pW0 + s0n + (cch + 4) * 8);
      c2.h = *(const half8*)(pW1 + s0n + cch * 8);
      c3.h = *(const half8*)(pW1 + s0n + (cch + 4) * 8);
    }

    // ---- S^T = K_eff(A) . Q^T(B), K=128, two 32-s blocks ----
    floatx16 sa0, sa1;
#pragma unroll
    for (int r = 0; r < 16; r++) { sa0[r] = 0.f; sa1[r] = 0.f; }
    const f16* ka0 = kbuf + l31 * KROW + lhi * 8;
    const f16* ka1 = kbuf + (32 + l31) * KROW + lhi * 8;
    __builtin_amdgcn_s_setprio(1);
#pragma unroll
    for (int kk = 0; kk < 8; kk++) {
      H8 x0, x1;
      const uint64_t* p0 = (const uint64_t*)(ka0 + kk * 16);
      const uint64_t* p1 = (const uint64_t*)(ka1 + kk * 16);
      x0.q[0] = p0[0]; x0.q[1] = p0[1];
      x1.q[0] = p1[0]; x1.q[1] = p1[1];
      sa0 = __builtin_amdgcn_mfma_f32_32x32x16_f16(x0.h, qf[kk], sa0, 0, 0, 0);
      sa1 = __builtin_amdgcn_mfma_f32_32x32x16_f16(x1.h, qf[kk], sa1, 0, 0, 0);
    }
    __builtin_amdgcn_s_setprio(0);
    __syncthreads();   // barrier A: kbuf reads done

    // ---- online softmax, base-2, raw v_exp_f32 ----
    float mt = -1e30f;
#pragma unroll
    for (int r = 0; r < 16; r++) { mt = fmaxf(mt, sa0[r]); mt = fmaxf(mt, sa1[r]); }
    mt = fmaxf(mt, __shfl_xor(mt, 32, 64));
    if (__any(mt > m_run)) {   // strict defer-rescale (exact)
      float m_new = fmaxf(m_run, mt);
      float alpha = __builtin_amdgcn_exp2f(m_run - m_new);
      l_run *= alpha;
#pragma unroll
      for (int ct = 0; ct < 4; ct++)
#pragma unroll
        for (int r = 0; r < 16; r++) oacc[ct][r] *= alpha;
      m_run = m_new;
    }
    float psum = 0.f;
#pragma unroll
    for (int r = 0; r < 16; r++) { sa0[r] = __builtin_amdgcn_exp2f(sa0[r] - m_run); psum += sa0[r]; }
#pragma unroll
    for (int r = 0; r < 16; r++) { sa1[r] = __builtin_amdgcn_exp2f(sa1[r] - m_run); psum += sa1[r]; }
    psum += __shfl_xor(psum, 32, 64);
    l_run += psum;

    // ---- build 4 PV B-fragments in-register (cvt_pkrtz + permlane32_swap) ----
    half8 bfr0, bfr1, bfr2, bfr3;
    {
      uint32_t pk[8];
#pragma unroll
      for (int g = 0; g < 8; ++g) {
        PK2 pu; pu.h = __builtin_amdgcn_cvt_pkrtz(sa0[2 * g], sa0[2 * g + 1]);
        pk[g] = pu.u;
      }
      int2v v0 = __builtin_amdgcn_permlane32_swap((int)pk[0], (int)pk[2], false, false);
      pk[0] = (uint32_t)v0.x; pk[2] = (uint32_t)v0.y;
      int2v v1 = __builtin_amdgcn_permlane32_swap((int)pk[1], (int)pk[3], false, false);
      pk[1] = (uint32_t)v1.x; pk[3] = (uint32_t)v1.y;
      int2v v2 = __builtin_amdgcn_permlane32_swap((int)pk[4], (int)pk[6], false, false);
      pk[4] = (uint32_t)v2.x; pk[6] = (uint32_t)v2.y;
      int2v v3 = __builtin_amdgcn_permlane32_swap((int)pk[5], (int)pk[7], false, false);
      pk[5] = (uint32_t)v3.x; pk[7] = (uint32_t)v3.y;
      BFU f0, f1;
      f0.u[0] = pk[0]; f0.u[1] = pk[1]; f0.u[2] = pk[2]; f0.u[3] = pk[3];
      f1.u[0] = pk[4]; f1.u[1] = pk[5]; f1.u[2] = pk[6]; f1.u[3] = pk[7];
      bfr0 = f0.h; bfr1 = f1.h;
    }
    {
      uint32_t pk[8];
#pragma unroll
      for (int g = 0; g < 8; ++g) {
        PK2 pu; pu.h = __builtin_amdgcn_cvt_pkrtz(sa1[2 * g], sa1[2 * g + 1]);
        pk[g] = pu.u;
      }
      int2v v0 = __builtin_amdgcn_permlane32_swap((int)pk[0], (int)pk[2], false, false);
      pk[0] = (uint32_t)v0.x; pk[2] = (uint32_t)v0.y;
      int2v v1 = __builtin_amdgcn_permlane32_swap((int)pk[1], (int)pk[3], false, false);
      pk[1] = (uint32_t)v1.x; pk[3] = (uint32_t)v1.y;
      int2v v2 = __builtin_amdgcn_permlane32_swap((int)pk[4], (int)pk[6], false, false);
      pk[4] = (uint32_t)v2.x; pk[6] = (uint32_t)v2.y;
      int2v v3 = __builtin_amdgcn_permlane32_swap((int)pk[5], (int)pk[7], false, false);
      pk[5] = (uint32_t)v3.x; pk[7] = (uint32_t)v3.y;
      BFU f0, f1;
      f0.u[0] = pk[0]; f0.u[1] = pk[1]; f0.u[2] = pk[2]; f0.u[3] = pk[3];
      f1.u[0] = pk[4]; f1.u[1] = pk[5]; f1.u[2] = pk[6]; f1.u[3] = pk[7];
      bfr2 = f0.h; bfr3 = f1.h;
    }

    // ---- PV: out^T = CW^T(A) . P^T(B), 4 ksteps (swizzled cc reads) ----
    __builtin_amdgcn_s_setprio(1);
#pragma unroll
    for (int ks = 0; ks < 4; ++ks) {
      half8 bfh = (ks == 0) ? bfr0 : (ks == 1) ? bfr1 : (ks == 2) ? bfr2 : bfr3;
#pragma unroll
      for (int ct = 0; ct < 4; ct++) {
        H8 af;
        const uint64_t* pa = (const uint64_t*)(cc + (ct * 32 + l31) * CROW +
                                               (((ks * 2 + lhi) ^ rsw) * 8));
        af.q[0] = pa[0]; af.q[1] = pa[1];
        oacc[ct] = __builtin_amdgcn_mfma_f32_32x32x16_f16(af.h, bfh, oacc[ct], 0, 0, 0);
      }
    }
    __builtin_amdgcn_s_setprio(0);

    // ---- commit staged tile i+1 (loads had the full S^T+softmax+PV window) ----
    if (pre) {
      uint64_t* d;
      d = (uint64_t*)(kbuf + kr * KROW + kc * 8);              d[0] = a0.q[0]; d[1] = a0.q[1];
      d = (uint64_t*)(kbuf + (kr + 32) * KROW + kc * 8);       d[0] = a1.q[0]; d[1] = a1.q[1];
      d = (uint64_t*)(kbuf + kr * KROW + 64 + kc * 8);         d[0] = r0.q[0]; d[1] = r0.q[1];
      d = (uint64_t*)(kbuf + (kr + 32) * KROW + 64 + kc * 8);  d[0] = r1.q[0]; d[1] = r1.q[1];
      d = (uint64_t*)(cn + cA * CROW + sw0);                   d[0] = c0.q[0]; d[1] = c0.q[1];
      d = (uint64_t*)(cn + cA * CROW + sw1);                   d[0] = c1.q[0]; d[1] = c1.q[1];
      d = (uint64_t*)(cn + (64 + cA) * CROW + sw0);            d[0] = c2.q[0]; d[1] = c2.q[1];
      d = (uint64_t*)(cn + (64 + cA) * CROW + sw1);            d[0] = c3.q[0]; d[1] = c3.q[1];
    }
    __syncthreads();   // barrier B: commits visible for next S^T / PV
  }

  // ---- epilogue: two q-halves through LDS, coalesced fp32 stores ----
  float inv = 1.0f / l_run;
  float* outp = out + ((size_t)(b * HQ_N + h) * QL_N + qt * 128) * DH_N;
#pragma unroll
  for (int p = 0; p < 2; ++p) {
    __syncthreads();
    if ((qloc >> 6) == p) {
      int lr = qloc & 63;
#pragma unroll
      for (int ct = 0; ct < 4; ct++)
#pragma unroll
        for (int r = 0; r < 16; r++) {
          int c = ct * 32 + (r & 3) + 8 * (r >> 2) + 4 * lhi;
          ot[lr * 133 + c] = oacc[ct][r] * inv;
        }
    }
    __syncthreads();
#pragma unroll
    for (int i = 0; i < 8; i++) {
      int flat = i * 256 + t; int q = flat >> 5, ch = flat & 31;
      float4 v;
      v.x = ot[q * 133 + ch * 4 + 0];
      v.y = ot[q * 133 + ch * 4 + 1];
      v.z = ot[q * 133 + ch * 4 + 2];
      v.w = ot[q * 133 + ch * 4 + 3];
      *(float4*)(outp + (size_t)(p * 64 + q) * DH_N + ch * 4) = v;
    }
  }
}

// ---------------------------------------------------------------------------
extern "C" void kernel_launch(void* const* d_in, const int* in_sizes, int n_in,
                              void* d_out, int out_size, void* d_ws, size_t ws_size,
                              hipStream_t stream) {
  (void)in_sizes; (void)n_in; (void)out_size; (void)ws_size;
  const float* Q   = (const float*)d_in[0];
  const float* C   = (const float*)d_in[1];
  const float* Kr  = (const float*)d_in[2];
  const float* Ul  = (const float*)d_in[3];
  const float* WUK = (const float*)d_in[4];
  const float* WUV = (const float*)d_in[5];
  float* out = (float*)d_out;
  char* ws = (char*)d_ws;
  // workspace carve (~11.8 MB)
  f16* Krf   = (f16*)ws;                   //  8388608 B
  f16* CWT   = (f16*)(ws + 8388608);       //  2097152 B
  f16* Kn    = (f16*)(ws + 10485760);      //  1048576 B
  f16* M2T2  = (f16*)(ws + 11534336);      //    32768 B
  f16* WUKh  = (f16*)(ws + 11567104);      //    65536 B
  f16* WUVT  = (f16*)(ws + 11632640);      //   131072 B

  hipLaunchKernelGGL(k_convert, dim3(2048), dim3(256), 0, stream, Kr, Krf);
  hipLaunchKernelGGL(k_weights, dim3(448),  dim3(256), 0, stream, Ul, WUK, WUV, M2T2, WUKh, WUVT);
  hipLaunchKernelGGL(k_kncw,    dim3(256),  dim3(256), 0, stream, C, WUKh, WUVT, Kn, CWT);
  hipLaunchKernelGGL(k_flash,   dim3(512),  dim3(256), 0, stream, Q, M2T2, Kn, Krf, CWT, out);
}

// Round 7
// 286.292 us; speedup vs baseline: 1.4065x; 1.0049x over previous
//
#include <hip/hip_runtime.h>
#include <stdint.h>

// ---- problem constants ----
#define B_N   2
#define HQ_N  32
#define HKV_N 8
#define QL_N  1024
#define SL_N  4096
#define DH_N  128
#define ROPE_N 64
#define RANK_N 512

typedef _Float16 f16;
typedef _Float16 half8 __attribute__((ext_vector_type(8)));
typedef __fp16 fp16x2 __attribute__((ext_vector_type(2)));
typedef float floatx16 __attribute__((ext_vector_type(16)));
typedef int int2v __attribute__((ext_vector_type(2)));

union H8 { half8 h; uint64_t q[2]; };
union PK2 { fp16x2 h; uint32_t u; };
union BFU { uint32_t u[4]; half8 h; };

__device__ inline half8 cvt8(float4 a, float4 b) {
  half8 o;
  o[0] = (f16)a.x; o[1] = (f16)a.y; o[2] = (f16)a.z; o[3] = (f16)a.w;
  o[4] = (f16)b.x; o[5] = (f16)b.y; o[6] = (f16)b.z; o[7] = (f16)b.w;
  return o;
}

// ---------------------------------------------------------------------------
// prep 1: fp32 -> fp16 convert of C_kv_t2 and K_rope_t2.  grid = 4096.
// ---------------------------------------------------------------------------
__global__ __launch_bounds__(256) void k_convert(const float* __restrict__ C,
                                                 const float* __restrict__ Kr,
                                                 f16* __restrict__ Cf,
                                                 f16* __restrict__ Krf) {
  const size_t NC = (size_t)B_N * SL_N * RANK_N;             // 4194304
  size_t idx = ((size_t)blockIdx.x * 256 + threadIdx.x) * 8; // covers 8388608
  const float* src;
  f16* dst;
  if (idx < NC) { src = C + idx;         dst = Cf + idx; }
  else          { src = Kr + (idx - NC); dst = Krf + (idx - NC); }
  float4 a = *(const float4*)(src);
  float4 b = *(const float4*)(src + 4);
  *(half8*)dst = cvt8(a, b);
}

// ---------------------------------------------------------------------------
// prep 2: weights: M2T2 (rotation), WUKh = f16(WUK), WUVT = f16(WUV^T).
// ---------------------------------------------------------------------------
__global__ __launch_bounds__(256) void k_weights(const float* __restrict__ Ul,
                                                 const float* __restrict__ WUK,
                                                 const float* __restrict__ WUV,
                                                 f16* __restrict__ M2T2,
                                                 f16* __restrict__ WUKh,
                                                 f16* __restrict__ WUVT) {
  int idx = blockIdx.x * 256 + threadIdx.x;
  if (idx < 16384) {
    int c = idx >> 7, d = idx & 127;
    float v = 0.f;
    if (c < 64) { if (d >= 64) v = Ul[c * 64 + (d - 64)]; }
    else        { if (d < 64)  v = Ul[(c - 64) * 64 + d]; }
    M2T2[idx] = (f16)v;
  } else if (idx < 49152) {
    int i = idx - 16384;
    WUKh[i] = (f16)WUK[i];
  } else {
    int i = idx - 49152;             // WUVT[c][r] = WUV[r][c]
    int c = i >> 9, r = i & 511;
    WUVT[i] = (f16)WUV[r * 128 + c];
  }
}

// ---------------------------------------------------------------------------
// prep 3 (fused): Kn[b][s][64] = C@WUK^T  AND  CWT[b][c][s] = (C@WUV)^T.
// grid = 256; chains split across waves; operands all f16 b128 loads.
// ---------------------------------------------------------------------------
__global__ __launch_bounds__(256) void k_kncw(const f16* __restrict__ Cf,
                                              const f16* __restrict__ WUKh,
                                              const f16* __restrict__ WUVT,
                                              f16* __restrict__ Kn,
                                              f16* __restrict__ CWT) {
  int t = threadIdx.x;
  int wave = t >> 6, lane = t & 63, l31 = lane & 31, lhi = lane >> 5;
  int b = blockIdx.x >> 7, st = blockIdx.x & 127;
  int s0 = st * 32;
  const f16* cp = Cf + ((size_t)b * SL_N + s0 + l31) * RANK_N + lhi * 8;
  floatx16 a0, a1;
#pragma unroll
  for (int r = 0; r < 16; r++) { a0[r] = 0.f; a1[r] = 0.f; }
  // chains: w0: Kn ct0+ct1 | w1: CWT ct0 | w2: CWT ct1+ct2 | w3: CWT ct3
#pragma unroll 4
  for (int kk = 0; kk < 32; ++kk) {
    half8 cf = *(const half8*)(cp + kk * 16);
    if (wave == 0) {
      half8 b0 = *(const half8*)(WUKh + (size_t)l31 * RANK_N + kk * 16 + lhi * 8);
      half8 b1 = *(const half8*)(WUKh + (size_t)(32 + l31) * RANK_N + kk * 16 + lhi * 8);
      a0 = __builtin_amdgcn_mfma_f32_32x32x16_f16(cf, b0, a0, 0, 0, 0);
      a1 = __builtin_amdgcn_mfma_f32_32x32x16_f16(cf, b1, a1, 0, 0, 0);
    } else if (wave == 1) {
      half8 w0 = *(const half8*)(WUVT + (size_t)l31 * RANK_N + kk * 16 + lhi * 8);
      a0 = __builtin_amdgcn_mfma_f32_32x32x16_f16(w0, cf, a0, 0, 0, 0);
    } else if (wave == 2) {
      half8 w1 = *(const half8*)(WUVT + (size_t)(32 + l31) * RANK_N + kk * 16 + lhi * 8);
      half8 w2 = *(const half8*)(WUVT + (size_t)(64 + l31) * RANK_N + kk * 16 + lhi * 8);
      a0 = __builtin_amdgcn_mfma_f32_32x32x16_f16(w1, cf, a0, 0, 0, 0);
      a1 = __builtin_amdgcn_mfma_f32_32x32x16_f16(w2, cf, a1, 0, 0, 0);
    } else {
      half8 w3 = *(const half8*)(WUVT + (size_t)(96 + l31) * RANK_N + kk * 16 + lhi * 8);
      a0 = __builtin_amdgcn_mfma_f32_32x32x16_f16(w3, cf, a0, 0, 0, 0);
    }
  }
  if (wave == 0) {
#pragma unroll
    for (int r = 0; r < 16; r++) {
      int row = (r & 3) + 8 * (r >> 2) + 4 * lhi;
      Kn[((size_t)b * SL_N + s0 + row) * 64 + l31]      = (f16)a0[r];
      Kn[((size_t)b * SL_N + s0 + row) * 64 + 32 + l31] = (f16)a1[r];
    }
  } else if (wave == 1) {
#pragma unroll
    for (int r = 0; r < 16; r++) {
      int row = (r & 3) + 8 * (r >> 2) + 4 * lhi;
      CWT[((size_t)b * DH_N + row) * SL_N + s0 + l31] = (f16)a0[r];
    }
  } else if (wave == 2) {
#pragma unroll
    for (int r = 0; r < 16; r++) {
      int row = (r & 3) + 8 * (r >> 2) + 4 * lhi;
      CWT[((size_t)b * DH_N + 32 + row) * SL_N + s0 + l31] = (f16)a0[r];
      CWT[((size_t)b * DH_N + 64 + row) * SL_N + s0 + l31] = (f16)a1[r];
    }
  } else {
#pragma unroll
    for (int r = 0; r < 16; r++) {
      int row = (r & 3) + 8 * (r >> 2) + 4 * lhi;
      CWT[((size_t)b * DH_N + 96 + row) * SL_N + s0 + l31] = (f16)a0[r];
    }
  }
}

// ---------------------------------------------------------------------------
// flash kernel, SOFTWARE-PIPELINED: per iter, one compute region does
// S^T(t+1) MFMA || softmax(t) VALU || PV(t) MFMA (independent chains ->
// in-wave pipe overlap), then barrier, commit(t+2), barrier.  kbuf is now
// double-buffered (LDS 68.6 KB -> 2 blocks/CU).  Loads for t+2 issued at
// region top -> full-region flight (r2/r6-proven).  No guards: final-iter
// loads/commits read <=16KB past array ends (inside ws), results discarded.
// grid = 512 = (b, h, q-tile 128).
// ---------------------------------------------------------------------------
#define KROW 132   // 264 B stride = 66 dw == 2 mod 32 -> 2-way (free)
#define CROW 68    // 136 B stride = 34 dw == 2 mod 32; chunk XOR-swizzled

__global__ __launch_bounds__(256, 2) void k_flash(
    const float* __restrict__ Q, const f16* __restrict__ M2T2,
    const f16* __restrict__ Kn, const f16* __restrict__ Krf,
    const f16* __restrict__ CWT, float* __restrict__ out) {
  __shared__ __align__(16) char smem[68608];
  f16* kbuf0 = (f16*)smem;                    // [64][132] 16896 B
  f16* kbuf1 = (f16*)(smem + 16896);
  f16* cbuf0 = (f16*)(smem + 33792);          // [128][68] 17408 B
  f16* cbuf1 = (f16*)(smem + 51200);
  f16* qs    = (f16*)smem;                    // prologue [128][132] 33792 B
  float* ot  = (float*)smem;                  // epilogue [64][133] 34048 B

  int t = threadIdx.x;
  int wave = t >> 6, lane = t & 63, l31 = lane & 31, lhi = lane >> 5;
  int qt = blockIdx.x & 7; int h = (blockIdx.x >> 3) & 31; int b = blockIdx.x >> 8;
  int kv = h >> 2;
  int qloc = wave * 32 + l31;

  const f16* Knb = Kn + (size_t)b * SL_N * 64;
  const f16* Kb  = Krf + (size_t)(b * HKV_N + kv) * SL_N * ROPE_N;
  const f16* Wb  = CWT + (size_t)b * DH_N * SL_N;

  // staging maps (block-unique, coalesced):
  int kr = t >> 3, kc = t & 7;
  int cA = t >> 2, cch = t & 3;
  const f16* pKn = Knb + (size_t)kr * 64 + kc * 8;
  const f16* pKr = Kb + (size_t)kr * ROPE_N + kc * 8;
  const f16* pW0 = Wb + (size_t)cA * SL_N;
  const f16* pW1 = Wb + (size_t)(64 + cA) * SL_N;
  int sw0 = ((cch) ^ (cA & 7)) * 8;
  int sw1 = ((cch + 4) ^ (cA & 7)) * 8;
  int rsw = l31 & 7;

  // persistent staging registers
  H8 a0, a1, r0, r1, c0v, c1v, c2v, c3v;

  auto issue = [&](int t2) {   // issue global loads for tile t2
    size_t ko = (size_t)t2 * (64 * 64);   // same stride for Kn (64w) and rope (64w)
    int soff = t2 * 64;
    a0.h  = *(const half8*)(pKn + ko);
    a1.h  = *(const half8*)(pKn + ko + 32 * 64);
    r0.h  = *(const half8*)(pKr + ko);
    r1.h  = *(const half8*)(pKr + ko + 32 * 64);
    c0v.h = *(const half8*)(pW0 + soff + cch * 8);
    c1v.h = *(const half8*)(pW0 + soff + (cch + 4) * 8);
    c2v.h = *(const half8*)(pW1 + soff + cch * 8);
    c3v.h = *(const half8*)(pW1 + soff + (cch + 4) * 8);
  };
  auto commit = [&](f16* kbW, f16* cbW) {
    uint64_t* d;
    d = (uint64_t*)(kbW + kr * KROW + kc * 8);             d[0] = a0.q[0]; d[1] = a0.q[1];
    d = (uint64_t*)(kbW + (kr + 32) * KROW + kc * 8);      d[0] = a1.q[0]; d[1] = a1.q[1];
    d = (uint64_t*)(kbW + kr * KROW + 64 + kc * 8);        d[0] = r0.q[0]; d[1] = r0.q[1];
    d = (uint64_t*)(kbW + (kr + 32) * KROW + 64 + kc * 8); d[0] = r1.q[0]; d[1] = r1.q[1];
    d = (uint64_t*)(cbW + cA * CROW + sw0);                d[0] = c0v.q[0]; d[1] = c0v.q[1];
    d = (uint64_t*)(cbW + cA * CROW + sw1);                d[0] = c1v.q[0]; d[1] = c1v.q[1];
    d = (uint64_t*)(cbW + (64 + cA) * CROW + sw0);         d[0] = c2v.q[0]; d[1] = c2v.q[1];
    d = (uint64_t*)(cbW + (64 + cA) * CROW + sw1);         d[0] = c3v.q[0]; d[1] = c3v.q[1];
  };

  // ---- fused Qeff prologue (tile-0 loads in flight underneath) ----
  issue(0);
  half8 qf[8];
  {
    const float* qp = Q + ((size_t)(b * HQ_N + h) * QL_N + qt * 128 + qloc) * DH_N + lhi * 8;
    floatx16 acc[4];
#pragma unroll
    for (int ct = 0; ct < 4; ct++)
#pragma unroll
      for (int r = 0; r < 16; r++) acc[ct][r] = 0.f;
#pragma unroll
    for (int kk = 0; kk < 8; ++kk) {
      float4 fa = *(const float4*)(qp + kk * 16);
      float4 fb = *(const float4*)(qp + kk * 16 + 4);
      half8 af = cvt8(fa, fb);
#pragma unroll
      for (int ct = 0; ct < 4; ct++) {
        half8 bf = *(const half8*)(M2T2 + (size_t)(ct * 32 + l31) * 128 + kk * 16 + lhi * 8);
        acc[ct] = __builtin_amdgcn_mfma_f32_32x32x16_f16(af, bf, acc[ct], 0, 0, 0);
      }
    }
    const float LOG2E = 1.44269504f;
#pragma unroll
    for (int ct = 0; ct < 4; ct++)
#pragma unroll
      for (int r = 0; r < 16; r++) {
        int row = (r & 3) + 8 * (r >> 2) + 4 * lhi;
        qs[(wave * 32 + row) * 132 + ct * 32 + l31] = (f16)(acc[ct][r] * LOG2E);
      }
  }
  __syncthreads();
#pragma unroll
  for (int kk = 0; kk < 8; kk++)
    qf[kk] = *(const half8*)(qs + (size_t)qloc * 132 + kk * 16 + lhi * 8);
  __syncthreads();   // qs dead; smem -> kbuf/cbuf

  floatx16 oacc[4];
#pragma unroll
  for (int ct = 0; ct < 4; ct++)
#pragma unroll
    for (int r = 0; r < 16; r++) oacc[ct][r] = 0.f;
  float m_run = -1e30f, l_run = 0.f;

  auto stmm = [&](const f16* kbN, floatx16& n0, floatx16& n1) {
#pragma unroll
    for (int r = 0; r < 16; r++) { n0[r] = 0.f; n1[r] = 0.f; }
    const f16* ka0 = kbN + l31 * KROW + lhi * 8;
    const f16* ka1 = kbN + (32 + l31) * KROW + lhi * 8;
#pragma unroll
    for (int kk = 0; kk < 8; kk++) {
      H8 x0, x1;
      const uint64_t* p0 = (const uint64_t*)(ka0 + kk * 16);
      const uint64_t* p1 = (const uint64_t*)(ka1 + kk * 16);
      x0.q[0] = p0[0]; x0.q[1] = p0[1];
      x1.q[0] = p1[0]; x1.q[1] = p1[1];
      n0 = __builtin_amdgcn_mfma_f32_32x32x16_f16(x0.h, qf[kk], n0, 0, 0, 0);
      n1 = __builtin_amdgcn_mfma_f32_32x32x16_f16(x1.h, qf[kk], n1, 0, 0, 0);
    }
  };
  auto softmax = [&](floatx16& s0, floatx16& s1) {
    float u[8];
#pragma unroll
    for (int g = 0; g < 4; g++)
      u[g] = fmaxf(fmaxf(s0[4 * g], s0[4 * g + 1]), fmaxf(s0[4 * g + 2], s0[4 * g + 3]));
#pragma unroll
    for (int g = 0; g < 4; g++)
      u[4 + g] = fmaxf(fmaxf(s1[4 * g], s1[4 * g + 1]), fmaxf(s1[4 * g + 2], s1[4 * g + 3]));
    float mt = fmaxf(fmaxf(fmaxf(u[0], u[1]), fmaxf(u[2], u[3])),
                     fmaxf(fmaxf(u[4], u[5]), fmaxf(u[6], u[7])));
    mt = fmaxf(mt, __shfl_xor(mt, 32, 64));
    if (__any(mt > m_run)) {   // strict defer-rescale (exact)
      float m_new = fmaxf(m_run, mt);
      float alpha = __builtin_amdgcn_exp2f(m_run - m_new);
      l_run *= alpha;
#pragma unroll
      for (int ct = 0; ct < 4; ct++)
#pragma unroll
        for (int r = 0; r < 16; r++) oacc[ct][r] *= alpha;
      m_run = m_new;
    }
    float p0 = 0.f, p1 = 0.f, p2 = 0.f, p3 = 0.f;
#pragma unroll
    for (int r = 0; r < 16; r += 4) {
      s0[r] = __builtin_amdgcn_exp2f(s0[r] - m_run);         p0 += s0[r];
      s0[r + 1] = __builtin_amdgcn_exp2f(s0[r + 1] - m_run); p1 += s0[r + 1];
      s0[r + 2] = __builtin_amdgcn_exp2f(s0[r + 2] - m_run); p2 += s0[r + 2];
      s0[r + 3] = __builtin_amdgcn_exp2f(s0[r + 3] - m_run); p3 += s0[r + 3];
    }
#pragma unroll
    for (int r = 0; r < 16; r += 4) {
      s1[r] = __builtin_amdgcn_exp2f(s1[r] - m_run);         p0 += s1[r];
      s1[r + 1] = __builtin_amdgcn_exp2f(s1[r + 1] - m_run); p1 += s1[r + 1];
      s1[r + 2] = __builtin_amdgcn_exp2f(s1[r + 2] - m_run); p2 += s1[r + 2];
      s1[r + 3] = __builtin_amdgcn_exp2f(s1[r + 3] - m_run); p3 += s1[r + 3];
    }
    float psum = (p0 + p1) + (p2 + p3);
    psum += __shfl_xor(psum, 32, 64);
    l_run += psum;
  };
  auto pack2 = [&](floatx16& s, half8& o0, half8& o1) {
    uint32_t pk[8];
#pragma unroll
    for (int g = 0; g < 8; ++g) {
      PK2 pu; pu.h = __builtin_amdgcn_cvt_pkrtz(s[2 * g], s[2 * g + 1]);
      pk[g] = pu.u;
    }
    int2v v0 = __builtin_amdgcn_permlane32_swap((int)pk[0], (int)pk[2], false, false);
    pk[0] = (uint32_t)v0.x; pk[2] = (uint32_t)v0.y;
    int2v v1 = __builtin_amdgcn_permlane32_swap((int)pk[1], (int)pk[3], false, false);
    pk[1] = (uint32_t)v1.x; pk[3] = (uint32_t)v1.y;
    int2v v2 = __builtin_amdgcn_permlane32_swap((int)pk[4], (int)pk[6], false, false);
    pk[4] = (uint32_t)v2.x; pk[6] = (uint32_t)v2.y;
    int2v v3 = __builtin_amdgcn_permlane32_swap((int)pk[5], (int)pk[7], false, false);
    pk[5] = (uint32_t)v3.x; pk[7] = (uint32_t)v3.y;
    BFU f0, f1;
    f0.u[0] = pk[0]; f0.u[1] = pk[1]; f0.u[2] = pk[2]; f0.u[3] = pk[3];
    f1.u[0] = pk[4]; f1.u[1] = pk[5]; f1.u[2] = pk[6]; f1.u[3] = pk[7];
    o0 = f0.h; o1 = f1.h;
  };
  auto pvmm = [&](const f16* cbC, half8 b0, half8 b1, half8 b2, half8 b3) {
#pragma unroll
    for (int ks = 0; ks < 4; ++ks) {
      half8 bfh = (ks == 0) ? b0 : (ks == 1) ? b1 : (ks == 2) ? b2 : b3;
#pragma unroll
      for (int ct = 0; ct < 4; ct++) {
        H8 af;
        const uint64_t* pa = (const uint64_t*)(cbC + (ct * 32 + l31) * CROW +
                                               (((ks * 2 + lhi) ^ rsw) * 8));
        af.q[0] = pa[0]; af.q[1] = pa[1];
        oacc[ct] = __builtin_amdgcn_mfma_f32_32x32x16_f16(af.h, bfh, oacc[ct], 0, 0, 0);
      }
    }
  };

  // pipelined sub-iteration: softmax+PV of tile t, S^T of tile t+1,
  // loads+commit of tile t+2.
  auto subit = [&](floatx16& cs0, floatx16& cs1, floatx16& ns0, floatx16& ns1,
                   const f16* kbN, const f16* cbC, f16* kbW, f16* cbW, int tt) {
    issue(tt + 2);
    __builtin_amdgcn_s_setprio(1);
    stmm(kbN, ns0, ns1);          // S^T(t+1): independent of softmax(t)
    softmax(cs0, cs1);
    half8 b0, b1, b2, b3;
    pack2(cs0, b0, b1);
    pack2(cs1, b2, b3);
    pvmm(cbC, b0, b1, b2, b3);
    __builtin_amdgcn_s_setprio(0);
    __syncthreads();              // all reads of kbW/cbW (prev tiles) done
    commit(kbW, cbW);
    __syncthreads();              // commits visible
  };

  // ---- pipeline prologue ----
  commit(kbuf0, cbuf0);   // tile 0
  issue(1);
  __syncthreads();
  floatx16 saA0, saA1, saB0, saB1;
  stmm(kbuf0, saA0, saA1);        // S^T(0)
  commit(kbuf1, cbuf1);           // tile 1 (different buffers: no barrier needed)
  __syncthreads();

  // ---- main loop: 64 tiles, 2 per unrolled pass ----
  for (int i2 = 0; i2 < 32; ++i2) {
    subit(saA0, saA1, saB0, saB1, kbuf1, cbuf0, kbuf0, cbuf0, 2 * i2);
    subit(saB0, saB1, saA0, saA1, kbuf0, cbuf1, kbuf1, cbuf1, 2 * i2 + 1);
  }

  // ---- epilogue: two q-halves through LDS, coalesced fp32 stores ----
  float inv = 1.0f / l_run;
  float* outp = out + ((size_t)(b * HQ_N + h) * QL_N + qt * 128) * DH_N;
#pragma unroll
  for (int p = 0; p < 2; ++p) {
    __syncthreads();
    if ((qloc >> 6) == p) {
      int lr = qloc & 63;
#pragma unroll
      for (int ct = 0; ct < 4; ct++)
#pragma unroll
        for (int r = 0; r < 16; r++) {
          int c = ct * 32 + (r & 3) + 8 * (r >> 2) + 4 * lhi;
          ot[lr * 133 + c] = oacc[ct][r] * inv;
        }
    }
    __syncthreads();
#pragma unroll
    for (int i = 0; i < 8; i++) {
      int flat = i * 256 + t; int q = flat >> 5, ch = flat & 31;
      float4 v;
      v.x = ot[q * 133 + ch * 4 + 0];
      v.y = ot[q * 133 + ch * 4 + 1];
      v.z = ot[q * 133 + ch * 4 + 2];
      v.w = ot[q * 133 + ch * 4 + 3];
      *(float4*)(outp + (size_t)(p * 64 + q) * DH_N + ch * 4) = v;
    }
  }
}

// ---------------------------------------------------------------------------
extern "C" void kernel_launch(void* const* d_in, const int* in_sizes, int n_in,
                              void* d_out, int out_size, void* d_ws, size_t ws_size,
                              hipStream_t stream) {
  (void)in_sizes; (void)n_in; (void)out_size; (void)ws_size;
  const float* Q   = (const float*)d_in[0];
  const float* C   = (const float*)d_in[1];
  const float* Kr  = (const float*)d_in[2];
  const float* Ul  = (const float*)d_in[3];
  const float* WUK = (const float*)d_in[4];
  const float* WUV = (const float*)d_in[5];
  float* out = (float*)d_out;
  char* ws = (char*)d_ws;
  // workspace carve (~20.2 MB); ordering gives OOB-read slack after Kn/Krf/CWT
  f16* Cf    = (f16*)ws;                   //  8388608 B
  f16* Krf   = (f16*)(ws + 8388608);       //  8388608 B
  f16* CWT   = (f16*)(ws + 16777216);      //  2097152 B
  f16* Kn    = (f16*)(ws + 18874368);      //  1048576 B
  f16* M2T2  = (f16*)(ws + 19922944);      //    32768 B
  f16* WUKh  = (f16*)(ws + 19955712);      //    65536 B
  f16* WUVT  = (f16*)(ws + 20021248);      //   131072 B

  hipLaunchKernelGGL(k_convert, dim3(4096), dim3(256), 0, stream, C, Kr, Cf, Krf);
  hipLaunchKernelGGL(k_weights, dim3(448),  dim3(256), 0, stream, Ul, WUK, WUV, M2T2, WUKh, WUVT);
  hipLaunchKernelGGL(k_kncw,    dim3(256),  dim3(256), 0, stream, Cf, WUKh, WUVT, Kn, CWT);
  hipLaunchKernelGGL(k_flash,   dim3(512),  dim3(256), 0, stream, Q, M2T2, Kn, Krf, CWT, out);
}